// Round 1
// baseline (869.596 us; speedup 1.0000x reference)
//
#include <hip/hip_runtime.h>

typedef unsigned short u16;
typedef float f32x4 __attribute__((ext_vector_type(4)));
typedef __bf16 bf16x8 __attribute__((ext_vector_type(8)));

__device__ __forceinline__ u16 f2bf(float f) {
  unsigned u = __float_as_uint(f);
  u += 0x7fffu + ((u >> 16) & 1u);
  return (u16)(u >> 16);
}

__device__ __forceinline__ f32x4 mfma16(bf16x8 a, bf16x8 b, f32x4 c) {
  return __builtin_amdgcn_mfma_f32_16x16x32_bf16(a, b, c, 0, 0, 0);
}

// ---------------------------------------------------------------------------
// Bias pack: bqkv[1536] = [bq | bk | bv]
// ---------------------------------------------------------------------------
__global__ void pack_bias_k(const float* __restrict__ bq, const float* __restrict__ bk,
                            const float* __restrict__ bv, float* __restrict__ bqkv) {
  int i = blockIdx.x * 256 + threadIdx.x;
  if (i < 512) bqkv[i] = bq[i];
  else if (i < 1024) bqkv[i] = bk[i - 512];
  else if (i < 1536) bqkv[i] = bv[i - 1024];
}

// ---------------------------------------------------------------------------
// Transpose+convert: out[C][R] (bf16) = in[R][C] (f32). Grid (C/32, R/32), block (32,8)
// ---------------------------------------------------------------------------
__global__ void tconv_w(const float* __restrict__ in, u16* __restrict__ out, int R, int C) {
  __shared__ float t[32][33];
  int c0 = blockIdx.x * 32, r0 = blockIdx.y * 32;
  int tx = threadIdx.x, ty = threadIdx.y;
#pragma unroll
  for (int j = 0; j < 4; ++j)
    t[ty * 4 + j][tx] = in[(size_t)(r0 + ty * 4 + j) * C + c0 + tx];
  __syncthreads();
#pragma unroll
  for (int j = 0; j < 4; ++j)
    out[(size_t)(c0 + ty * 4 + j) * R + r0 + tx] = f2bf(t[tx][ty * 4 + j]);
}

// ---------------------------------------------------------------------------
// V transpose (bf16->bf16): per batch z, in = qkv rows [4096] cols[1024..1536) stride 1536
// out = Vt[b][512][4096]. Grid (16,128,4), block (32,8)
// ---------------------------------------------------------------------------
__global__ void tpose_v(const u16* __restrict__ qkv, u16* __restrict__ Vt) {
  __shared__ u16 t[32][41];
  int b = blockIdx.z;
  int c0 = blockIdx.x * 32, r0 = blockIdx.y * 32;
  int tx = threadIdx.x, ty = threadIdx.y;
  const u16* in = qkv + (size_t)b * 4096 * 1536 + 1024;
  u16* outp = Vt + (size_t)b * 512 * 4096;
#pragma unroll
  for (int j = 0; j < 4; ++j)
    t[ty * 4 + j][tx] = in[(size_t)(r0 + ty * 4 + j) * 1536 + c0 + tx];
  __syncthreads();
#pragma unroll
  for (int j = 0; j < 4; ++j)
    outp[(size_t)(c0 + ty * 4 + j) * 4096 + r0 + tx] = t[tx][ty * 4 + j];
}

// ---------------------------------------------------------------------------
// LayerNorm: x f32 [R][512] -> out bf16 [R][512]. 1 wave per row, 4 rows/block.
// ---------------------------------------------------------------------------
__global__ __launch_bounds__(256) void ln_fwd(const float* __restrict__ x,
                                              const float* __restrict__ gw,
                                              const float* __restrict__ bw,
                                              u16* __restrict__ out) {
  int row = blockIdx.x * 4 + (threadIdx.x >> 6);
  int lane = threadIdx.x & 63;
  const float* xr = x + (size_t)row * 512;
  float xv[8], gv[8], bv[8];
  *(float4*)&xv[0] = *(const float4*)(xr + lane * 8);
  *(float4*)&xv[4] = *(const float4*)(xr + lane * 8 + 4);
  *(float4*)&gv[0] = *(const float4*)(gw + lane * 8);
  *(float4*)&gv[4] = *(const float4*)(gw + lane * 8 + 4);
  *(float4*)&bv[0] = *(const float4*)(bw + lane * 8);
  *(float4*)&bv[4] = *(const float4*)(bw + lane * 8 + 4);
  float sum = 0.f, sq = 0.f;
#pragma unroll
  for (int j = 0; j < 8; ++j) { sum += xv[j]; sq += xv[j] * xv[j]; }
#pragma unroll
  for (int d = 1; d < 64; d <<= 1) {
    sum += __shfl_xor(sum, d);
    sq += __shfl_xor(sq, d);
  }
  float mean = sum * (1.f / 512.f);
  float var = sq * (1.f / 512.f) - mean * mean;
  float rstd = rsqrtf(var + 1e-5f);
  union { uint4 u; u16 h[8]; } ob;
#pragma unroll
  for (int j = 0; j < 8; ++j)
    ob.h[j] = f2bf((xv[j] - mean) * rstd * gv[j] + bv[j]);
  *(uint4*)(out + (size_t)row * 512 + lane * 8) = ob.u;
}

// ---------------------------------------------------------------------------
// GEMM: C[M][N] = A[M][K](bf16) * Bt[N][K](bf16)^T  + epilogue
// EPI 1: out bf16 = acc + bias       (QKV)
// EPI 2: out bf16 = gelu(acc + bias) (MLP1)
// EPI 3: out f32  = acc + bias + res (Wo-proj, MLP2)
// 128x128 tile, BK=64, 256 threads (4 waves, 2x2), wave does 64x64 (4x4 frags)
// ---------------------------------------------------------------------------
template <int EPI>
__global__ __launch_bounds__(256, 2) void gemm_bt(const u16* __restrict__ A,
                                                  const u16* __restrict__ Bt,
                                                  const float* __restrict__ bias,
                                                  const float* __restrict__ res,
                                                  void* __restrict__ out,
                                                  int M, int N, int K) {
  __shared__ u16 As[128][72];
  __shared__ u16 Bs[128][72];
  const int tid = threadIdx.x;
  const int lane = tid & 63, w = tid >> 6;
  const int wr = w >> 1, wc = w & 1;
  const int m0 = blockIdx.x * 128, n0 = blockIdx.y * 128;
  const int lh = lane >> 4, ll = lane & 15;

  f32x4 acc[4][4] = {};
  const int nk = K >> 6;
  for (int kt = 0; kt < nk; ++kt) {
    const int k0 = kt << 6;
#pragma unroll
    for (int c = 0; c < 4; ++c) {
      int chunk = c * 256 + tid;
      int row = chunk >> 3, c8 = (chunk & 7) * 8;
      uint4 va = *(const uint4*)(A + (size_t)(m0 + row) * K + k0 + c8);
      uint4 vb = *(const uint4*)(Bt + (size_t)(n0 + row) * K + k0 + c8);
      *(uint4*)&As[row][c8] = va;
      *(uint4*)&Bs[row][c8] = vb;
    }
    __syncthreads();
#pragma unroll
    for (int ks = 0; ks < 2; ++ks) {
      bf16x8 a[4], b[4];
#pragma unroll
      for (int m = 0; m < 4; ++m) a[m] = *(const bf16x8*)&As[wr * 64 + m * 16 + ll][ks * 32 + lh * 8];
#pragma unroll
      for (int n = 0; n < 4; ++n) b[n] = *(const bf16x8*)&Bs[wc * 64 + n * 16 + ll][ks * 32 + lh * 8];
#pragma unroll
      for (int m = 0; m < 4; ++m)
#pragma unroll
        for (int n = 0; n < 4; ++n)
          acc[m][n] = mfma16(a[m], b[n], acc[m][n]);
    }
    __syncthreads();
  }
  // epilogue (C/D layout: col = lane&15, row = (lane>>4)*4 + i, verified m89)
#pragma unroll
  for (int m = 0; m < 4; ++m) {
    int row = m0 + wr * 64 + m * 16 + lh * 4;
#pragma unroll
    for (int n = 0; n < 4; ++n) {
      int col = n0 + wc * 64 + n * 16 + ll;
      float bv = bias[col];
#pragma unroll
      for (int i = 0; i < 4; ++i) {
        float v = acc[m][n][i] + bv;
        size_t idx = (size_t)(row + i) * N + col;
        if (EPI == 2) v = 0.5f * v * (1.f + erff(v * 0.70710678118654752f));
        if (EPI == 3)
          ((float*)out)[idx] = v + res[idx];
        else
          ((u16*)out)[idx] = f2bf(v);
      }
    }
  }
}

// ---------------------------------------------------------------------------
// Flash attention: B=4, S=4096, D=512, single head, scale 1/sqrt(512).
// Grid 256 (batch*64 qtiles), block 512 (8 waves). Q-tile 64 rows.
// Wave w: group g=w>>2 owns Q rows [32g,32g+32); wq=w&3 is its kv/d slice.
// Q held in registers. K tiles [64][512] staged in 2 d-chunks; V^T staged
// from pre-transposed Vt global. Online softmax with cross-wave LDS partials.
// ---------------------------------------------------------------------------
__global__ __launch_bounds__(512) void fa_kernel(const u16* __restrict__ qkv,
                                                 const u16* __restrict__ Vtg,
                                                 u16* __restrict__ o) {
  __shared__ u16 KV[18432];           // K chunk [64][264] or Vt chunk [256][72]
  __shared__ u16 Ps[2][32][72];       // P tiles per group
  __shared__ float redm[2][4][32];
  __shared__ float redl[2][4][32];

  const int tid = threadIdx.x;
  const int lane = tid & 63;
  const int w = tid >> 6;
  const int g = w >> 2, wq = w & 3;
  const int lh = lane >> 4, ll = lane & 15;
  const int batch = blockIdx.x >> 6;
  const int qt = blockIdx.x & 63;
  const int qrow0 = qt * 64;

  const u16* qb = qkv + (size_t)batch * 4096 * 1536;
  const u16* kb = qb + 512;
  const u16* vt = Vtg + (size_t)batch * 512 * 4096;

  // Q fragments in registers: qf[f][ks] covers rows 32g+16f+ll, d = ks*32+lh*8..+8
  bf16x8 qf[2][16];
#pragma unroll
  for (int f = 0; f < 2; ++f) {
    const u16* qr = qb + (size_t)(qrow0 + g * 32 + f * 16 + ll) * 1536;
#pragma unroll
    for (int ks = 0; ks < 16; ++ks)
      qf[f][ks] = *(const bf16x8*)(qr + ks * 32 + lh * 8);
  }

  f32x4 accO[2][2][4] = {};  // [dchunk][f][cf]
  f32x4 m_run[2], l_run[2];
#pragma unroll
  for (int f = 0; f < 2; ++f)
#pragma unroll
    for (int i = 0; i < 4; ++i) { m_run[f][i] = -1e30f; l_run[f][i] = 0.f; }

  const float scale = 0.044194173824159216f;  // 512^-0.5

  for (int kt = 0; kt < 64; ++kt) {
    const int kv0 = kt * 64;
    f32x4 s[2] = {};
    // ---- QK^T: S[32][16 slice] per wave ----
#pragma unroll
    for (int dc = 0; dc < 2; ++dc) {
#pragma unroll
      for (int c = 0; c < 4; ++c) {
        int chunk = c * 512 + tid;
        int r = chunk >> 5, cc = (chunk & 31) * 8;
        uint4 v = *(const uint4*)(kb + (size_t)(kv0 + r) * 1536 + dc * 256 + cc);
        *(uint4*)&KV[r * 264 + cc] = v;
      }
      __syncthreads();
#pragma unroll
      for (int ks = 0; ks < 8; ++ks) {
        bf16x8 bfrag = *(const bf16x8*)&KV[(wq * 16 + ll) * 264 + ks * 32 + lh * 8];
        s[0] = mfma16(qf[0][dc * 8 + ks], bfrag, s[0]);
        s[1] = mfma16(qf[1][dc * 8 + ks], bfrag, s[1]);
      }
      __syncthreads();
    }
    // ---- online softmax ----
    f32x4 rm[2];
#pragma unroll
    for (int f = 0; f < 2; ++f)
#pragma unroll
      for (int i = 0; i < 4; ++i) {
        s[f][i] *= scale;
        rm[f][i] = s[f][i];
      }
#pragma unroll
    for (int d = 1; d < 16; d <<= 1)
#pragma unroll
      for (int f = 0; f < 2; ++f)
#pragma unroll
        for (int i = 0; i < 4; ++i)
          rm[f][i] = fmaxf(rm[f][i], __shfl_xor(rm[f][i], d));
    if (ll == 0) {
#pragma unroll
      for (int f = 0; f < 2; ++f)
        *(f32x4*)&redm[g][wq][f * 16 + lh * 4] = rm[f];
    }
    __syncthreads();
    f32x4 mnew[2], alpha[2], p[2], rs[2];
#pragma unroll
    for (int f = 0; f < 2; ++f) {
      f32x4 t = *(const f32x4*)&redm[g][0][f * 16 + lh * 4];
#pragma unroll
      for (int wq2 = 1; wq2 < 4; ++wq2) {
        f32x4 t2 = *(const f32x4*)&redm[g][wq2][f * 16 + lh * 4];
#pragma unroll
        for (int i = 0; i < 4; ++i) t[i] = fmaxf(t[i], t2[i]);
      }
#pragma unroll
      for (int i = 0; i < 4; ++i) {
        mnew[f][i] = fmaxf(m_run[f][i], t[i]);
        alpha[f][i] = __expf(m_run[f][i] - mnew[f][i]);
        p[f][i] = __expf(s[f][i] - mnew[f][i]);
        rs[f][i] = p[f][i];
      }
    }
#pragma unroll
    for (int d = 1; d < 16; d <<= 1)
#pragma unroll
      for (int f = 0; f < 2; ++f)
#pragma unroll
        for (int i = 0; i < 4; ++i)
          rs[f][i] += __shfl_xor(rs[f][i], d);
    if (ll == 0) {
#pragma unroll
      for (int f = 0; f < 2; ++f)
        *(f32x4*)&redl[g][wq][f * 16 + lh * 4] = rs[f];
    }
    // P -> LDS (bf16)
#pragma unroll
    for (int f = 0; f < 2; ++f)
#pragma unroll
      for (int i = 0; i < 4; ++i)
        Ps[g][f * 16 + lh * 4 + i][wq * 16 + ll] = f2bf(p[f][i]);
    // rescale O
#pragma unroll
    for (int dc = 0; dc < 2; ++dc)
#pragma unroll
      for (int f = 0; f < 2; ++f)
#pragma unroll
        for (int cf = 0; cf < 4; ++cf)
#pragma unroll
          for (int i = 0; i < 4; ++i)
            accO[dc][f][cf][i] *= alpha[f][i];
    __syncthreads();
#pragma unroll
    for (int f = 0; f < 2; ++f) {
      f32x4 t = *(const f32x4*)&redl[g][0][f * 16 + lh * 4];
#pragma unroll
      for (int wq2 = 1; wq2 < 4; ++wq2) {
        f32x4 t2 = *(const f32x4*)&redl[g][wq2][f * 16 + lh * 4];
#pragma unroll
        for (int i = 0; i < 4; ++i) t[i] += t2[i];
      }
#pragma unroll
      for (int i = 0; i < 4; ++i) {
        l_run[f][i] = l_run[f][i] * alpha[f][i] + t[i];
        m_run[f][i] = mnew[f][i];
      }
    }
    // ---- PV: O[32][128 slice] per wave, 2 d-chunks of 256 ----
#pragma unroll
    for (int dc = 0; dc < 2; ++dc) {
#pragma unroll
      for (int c = 0; c < 4; ++c) {
        int chunk = c * 512 + tid;
        int r = chunk >> 3, cc = (chunk & 7) * 8;
        uint4 v = *(const uint4*)(vt + (size_t)(dc * 256 + r) * 4096 + kv0 + cc);
        *(uint4*)&KV[r * 72 + cc] = v;
      }
      __syncthreads();
#pragma unroll
      for (int ksP = 0; ksP < 2; ++ksP) {
        bf16x8 pa0 = *(const bf16x8*)&Ps[g][ll][ksP * 32 + lh * 8];
        bf16x8 pa1 = *(const bf16x8*)&Ps[g][16 + ll][ksP * 32 + lh * 8];
#pragma unroll
        for (int cf = 0; cf < 4; ++cf) {
          bf16x8 vb = *(const bf16x8*)&KV[(wq * 64 + cf * 16 + ll) * 72 + ksP * 32 + lh * 8];
          accO[dc][0][cf] = mfma16(pa0, vb, accO[dc][0][cf]);
          accO[dc][1][cf] = mfma16(pa1, vb, accO[dc][1][cf]);
        }
      }
      __syncthreads();
    }
  }
  // ---- finalize: O /= l ----
  f32x4 inv[2];
#pragma unroll
  for (int f = 0; f < 2; ++f)
#pragma unroll
    for (int i = 0; i < 4; ++i) inv[f][i] = 1.f / l_run[f][i];
#pragma unroll
  for (int dc = 0; dc < 2; ++dc)
#pragma unroll
    for (int f = 0; f < 2; ++f)
#pragma unroll
      for (int cf = 0; cf < 4; ++cf) {
        int row = qrow0 + g * 32 + f * 16 + lh * 4;
        int col = dc * 256 + wq * 64 + cf * 16 + ll;
        u16* op = o + (size_t)(batch * 4096 + row) * 512 + col;
#pragma unroll
        for (int i = 0; i < 4; ++i)
          op[(size_t)i * 512] = f2bf(accO[dc][f][cf][i] * inv[f][i]);
      }
}

// ---------------------------------------------------------------------------
extern "C" void kernel_launch(void* const* d_in, const int* in_sizes, int n_in,
                              void* d_out, int out_size, void* d_ws, size_t ws_size,
                              hipStream_t stream) {
  const float* x     = (const float*)d_in[0];
  const float* ln1g  = (const float*)d_in[1];
  const float* ln1b  = (const float*)d_in[2];
  const float* Wq    = (const float*)d_in[3];
  const float* bq    = (const float*)d_in[4];
  const float* Wk    = (const float*)d_in[5];
  const float* bk    = (const float*)d_in[6];
  const float* Wv    = (const float*)d_in[7];
  const float* bv    = (const float*)d_in[8];
  const float* Wo    = (const float*)d_in[9];
  const float* bo    = (const float*)d_in[10];
  const float* ln2g  = (const float*)d_in[11];
  const float* ln2b  = (const float*)d_in[12];
  const float* W1    = (const float*)d_in[13];
  const float* b1    = (const float*)d_in[14];
  const float* W2    = (const float*)d_in[15];
  const float* b2    = (const float*)d_in[16];

  // workspace layout (120 MB total)
  u16* Wqkvt = (u16*)d_ws;                     // [1536][512]
  u16* Wot   = Wqkvt + 786432;                 // [512][512]
  u16* W1t   = Wot + 262144;                   // [2048][512]
  u16* W2t   = W1t + 1048576;                  // [512][2048]
  float* bqkv = (float*)(W2t + 1048576);       // [1536]
  char* base = (char*)d_ws;
  u16* qkvb = (u16*)(base + (8u << 20));       // [16384][1536] bf16
  u16* Vt   = qkvb + (size_t)16384 * 1536;     // [4][512][4096] bf16
  u16* m1   = qkvb;                            // alias: [16384][2048] bf16 (qkv+Vt dead)
  u16* hb   = (u16*)(base + (8u << 20) + 67108864u);   // h / o / h2 [16384][512] bf16
  float* x1 = (float*)(base + (8u << 20) + 67108864u + 16777216u);  // [16384][512] f32

  dim3 tb(32, 8);
  pack_bias_k<<<6, 256, 0, stream>>>(bq, bk, bv, bqkv);
  tconv_w<<<dim3(16, 16), tb, 0, stream>>>(Wq, Wqkvt, 512, 512);
  tconv_w<<<dim3(16, 16), tb, 0, stream>>>(Wk, Wqkvt + 262144, 512, 512);
  tconv_w<<<dim3(16, 16), tb, 0, stream>>>(Wv, Wqkvt + 524288, 512, 512);
  tconv_w<<<dim3(16, 16), tb, 0, stream>>>(Wo, Wot, 512, 512);
  tconv_w<<<dim3(64, 16), tb, 0, stream>>>(W1, W1t, 512, 2048);
  tconv_w<<<dim3(16, 64), tb, 0, stream>>>(W2, W2t, 2048, 512);

  // h = LN1(x)
  ln_fwd<<<4096, 256, 0, stream>>>(x, ln1g, ln1b, hb);
  // qkv = h @ Wqkv + b
  gemm_bt<1><<<dim3(128, 12), 256, 0, stream>>>(hb, Wqkvt, bqkv, nullptr, qkvb, 16384, 1536, 512);
  // Vt = transpose(v)
  tpose_v<<<dim3(16, 128, 4), tb, 0, stream>>>(qkvb, Vt);
  // o = attention(q,k,v)   (overwrites h, which is dead)
  fa_kernel<<<256, 512, 0, stream>>>(qkvb, Vt, hb);
  // x1 = x + o @ Wo + bo
  gemm_bt<3><<<dim3(128, 4), 256, 0, stream>>>(hb, Wot, bo, x, x1, 16384, 512, 512);
  // h2 = LN2(x1)  (overwrites o, dead)
  ln_fwd<<<4096, 256, 0, stream>>>(x1, ln2g, ln2b, hb);
  // m1 = gelu(h2 @ W1 + b1)   (overwrites qkv/Vt, dead)
  gemm_bt<2><<<dim3(128, 16), 256, 0, stream>>>(hb, W1t, b1, nullptr, m1, 16384, 2048, 512);
  // out = x1 + m1 @ W2 + b2
  gemm_bt<3><<<dim3(128, 4), 256, 0, stream>>>(m1, W2t, b2, x1, (float*)d_out, 16384, 512, 2048);
}

// Round 3
// 694.371 us; speedup vs baseline: 1.2524x; 1.2524x over previous
//
#include <hip/hip_runtime.h>

typedef unsigned short u16;
typedef float f32x4 __attribute__((ext_vector_type(4)));
typedef __bf16 bf16x8 __attribute__((ext_vector_type(8)));

__device__ __forceinline__ u16 f2bf(float f) {
  unsigned u = __float_as_uint(f);
  u += 0x7fffu + ((u >> 16) & 1u);
  return (u16)(u >> 16);
}

__device__ __forceinline__ f32x4 mfma16(bf16x8 a, bf16x8 b, f32x4 c) {
  return __builtin_amdgcn_mfma_f32_16x16x32_bf16(a, b, c, 0, 0, 0);
}

// ---------------------------------------------------------------------------
// Bias pack: bqkv[1536] = [bq | bk | bv]
// ---------------------------------------------------------------------------
__global__ void pack_bias_k(const float* __restrict__ bq, const float* __restrict__ bk,
                            const float* __restrict__ bv, float* __restrict__ bqkv) {
  int i = blockIdx.x * 256 + threadIdx.x;
  if (i < 512) bqkv[i] = bq[i];
  else if (i < 1024) bqkv[i] = bk[i - 512];
  else if (i < 1536) bqkv[i] = bv[i - 1024];
}

// ---------------------------------------------------------------------------
// Transpose+convert: out[C][R] (bf16) = in[R][C] (f32). Grid (C/32, R/32), block (32,8)
// ---------------------------------------------------------------------------
__global__ void tconv_w(const float* __restrict__ in, u16* __restrict__ out, int R, int C) {
  __shared__ float t[32][33];
  int c0 = blockIdx.x * 32, r0 = blockIdx.y * 32;
  int tx = threadIdx.x, ty = threadIdx.y;
#pragma unroll
  for (int j = 0; j < 4; ++j)
    t[ty * 4 + j][tx] = in[(size_t)(r0 + ty * 4 + j) * C + c0 + tx];
  __syncthreads();
#pragma unroll
  for (int j = 0; j < 4; ++j)
    out[(size_t)(c0 + ty * 4 + j) * R + r0 + tx] = f2bf(t[tx][ty * 4 + j]);
}

// ---------------------------------------------------------------------------
// V transpose (bf16->bf16): per batch z, in = qkv rows [4096] cols[1024..1536) stride 1536
// out = Vt[b][512][4096]. Grid (16,128,4), block (32,8)
// ---------------------------------------------------------------------------
__global__ void tpose_v(const u16* __restrict__ qkv, u16* __restrict__ Vt) {
  __shared__ u16 t[32][41];
  int b = blockIdx.z;
  int c0 = blockIdx.x * 32, r0 = blockIdx.y * 32;
  int tx = threadIdx.x, ty = threadIdx.y;
  const u16* in = qkv + (size_t)b * 4096 * 1536 + 1024;
  u16* outp = Vt + (size_t)b * 512 * 4096;
#pragma unroll
  for (int j = 0; j < 4; ++j)
    t[ty * 4 + j][tx] = in[(size_t)(r0 + ty * 4 + j) * 1536 + c0 + tx];
  __syncthreads();
#pragma unroll
  for (int j = 0; j < 4; ++j)
    outp[(size_t)(c0 + ty * 4 + j) * 4096 + r0 + tx] = t[tx][ty * 4 + j];
}

// ---------------------------------------------------------------------------
// LayerNorm: x f32 [R][512] -> out bf16 [R][512]. 1 wave per row, 4 rows/block.
// ---------------------------------------------------------------------------
__global__ __launch_bounds__(256) void ln_fwd(const float* __restrict__ x,
                                              const float* __restrict__ gw,
                                              const float* __restrict__ bw,
                                              u16* __restrict__ out) {
  int row = blockIdx.x * 4 + (threadIdx.x >> 6);
  int lane = threadIdx.x & 63;
  const float* xr = x + (size_t)row * 512;
  float xv[8], gv[8], bv[8];
  *(float4*)&xv[0] = *(const float4*)(xr + lane * 8);
  *(float4*)&xv[4] = *(const float4*)(xr + lane * 8 + 4);
  *(float4*)&gv[0] = *(const float4*)(gw + lane * 8);
  *(float4*)&gv[4] = *(const float4*)(gw + lane * 8 + 4);
  *(float4*)&bv[0] = *(const float4*)(bw + lane * 8);
  *(float4*)&bv[4] = *(const float4*)(bw + lane * 8 + 4);
  float sum = 0.f, sq = 0.f;
#pragma unroll
  for (int j = 0; j < 8; ++j) { sum += xv[j]; sq += xv[j] * xv[j]; }
#pragma unroll
  for (int d = 1; d < 64; d <<= 1) {
    sum += __shfl_xor(sum, d);
    sq += __shfl_xor(sq, d);
  }
  float mean = sum * (1.f / 512.f);
  float var = sq * (1.f / 512.f) - mean * mean;
  float rstd = rsqrtf(var + 1e-5f);
  union { uint4 u; u16 h[8]; } ob;
#pragma unroll
  for (int j = 0; j < 8; ++j)
    ob.h[j] = f2bf((xv[j] - mean) * rstd * gv[j] + bv[j]);
  *(uint4*)(out + (size_t)row * 512 + lane * 8) = ob.u;
}

// ---------------------------------------------------------------------------
// Row softmax in-place on bf16 scores [rows][4096]; applies scale 1/sqrt(512).
// 1 block (4 waves) per row; each thread owns 16 contiguous elements.
// ---------------------------------------------------------------------------
__global__ __launch_bounds__(256) void softmax_rows(u16* __restrict__ sc) {
  __shared__ float red[8];
  const int tid = threadIdx.x;
  const int lane = tid & 63, w = tid >> 6;
  u16* sr = sc + (size_t)blockIdx.x * 4096 + tid * 16;
  uint4 a = *(const uint4*)sr;
  uint4 b = *(const uint4*)(sr + 8);
  const u16* ap = (const u16*)&a;
  const u16* bp = (const u16*)&b;
  float v[16];
#pragma unroll
  for (int i = 0; i < 8; ++i) {
    v[i] = __uint_as_float((unsigned)ap[i] << 16);
    v[8 + i] = __uint_as_float((unsigned)bp[i] << 16);
  }
  float m = v[0];
#pragma unroll
  for (int i = 1; i < 16; ++i) m = fmaxf(m, v[i]);
#pragma unroll
  for (int d = 1; d < 64; d <<= 1) m = fmaxf(m, __shfl_xor(m, d));
  if (lane == 0) red[w] = m;
  __syncthreads();
  m = fmaxf(fmaxf(red[0], red[1]), fmaxf(red[2], red[3]));
  const float scale = 0.044194173824159216f;  // 512^-0.5
  float s = 0.f;
#pragma unroll
  for (int i = 0; i < 16; ++i) {
    v[i] = __expf((v[i] - m) * scale);
    s += v[i];
  }
#pragma unroll
  for (int d = 1; d < 64; d <<= 1) s += __shfl_xor(s, d);
  if (lane == 0) red[4 + w] = s;
  __syncthreads();
  s = (red[4] + red[5]) + (red[6] + red[7]);
  float inv = 1.f / s;
  union { uint4 u; u16 h[8]; } o1, o2;
#pragma unroll
  for (int i = 0; i < 8; ++i) {
    o1.h[i] = f2bf(v[i] * inv);
    o2.h[i] = f2bf(v[8 + i] * inv);
  }
  *(uint4*)sr = o1.u;
  *(uint4*)(sr + 8) = o2.u;
}

// ---------------------------------------------------------------------------
// GEMM: C[M][N] = A[M][K](bf16, row stride lda) * Bt[N][K](bf16, row stride ldb)^T
// Batched over blockIdx.z with element strides sA/sB/sC.
// EPI 0: out bf16 = acc               (scores, PV)
// EPI 1: out bf16 = acc + bias        (QKV)
// EPI 2: out bf16 = gelu(acc + bias)  (MLP1)
// EPI 3: out f32  = acc + bias + res  (Wo-proj, MLP2)
// 128x128 tile, BK=64, 256 threads (4 waves, 2x2), wave does 64x64 (4x4 frags)
// ---------------------------------------------------------------------------
template <int EPI>
__global__ __launch_bounds__(256, 2) void gemm_bt(const u16* __restrict__ A, int lda, size_t sA,
                                                  const u16* __restrict__ Bt, int ldb, size_t sB,
                                                  const float* __restrict__ bias,
                                                  const float* __restrict__ res,
                                                  void* __restrict__ out, int ldc, size_t sC,
                                                  int M, int N, int K) {
  __shared__ u16 As[128][72];
  __shared__ u16 Bs[128][72];
  const int tid = threadIdx.x;
  const int lane = tid & 63, w = tid >> 6;
  const int wr = w >> 1, wc = w & 1;
  const int m0 = blockIdx.x * 128, n0 = blockIdx.y * 128;
  const int lh = lane >> 4, ll = lane & 15;
  A += (size_t)blockIdx.z * sA;
  Bt += (size_t)blockIdx.z * sB;

  f32x4 acc[4][4] = {};
  const int nk = K >> 6;
  for (int kt = 0; kt < nk; ++kt) {
    const int k0 = kt << 6;
#pragma unroll
    for (int c = 0; c < 4; ++c) {
      int chunk = c * 256 + tid;
      int row = chunk >> 3, c8 = (chunk & 7) * 8;
      uint4 va = *(const uint4*)(A + (size_t)(m0 + row) * lda + k0 + c8);
      uint4 vb = *(const uint4*)(Bt + (size_t)(n0 + row) * ldb + k0 + c8);
      *(uint4*)&As[row][c8] = va;
      *(uint4*)&Bs[row][c8] = vb;
    }
    __syncthreads();
#pragma unroll
    for (int ks = 0; ks < 2; ++ks) {
      bf16x8 a[4], b[4];
#pragma unroll
      for (int m = 0; m < 4; ++m) a[m] = *(const bf16x8*)&As[wr * 64 + m * 16 + ll][ks * 32 + lh * 8];
#pragma unroll
      for (int n = 0; n < 4; ++n) b[n] = *(const bf16x8*)&Bs[wc * 64 + n * 16 + ll][ks * 32 + lh * 8];
#pragma unroll
      for (int m = 0; m < 4; ++m)
#pragma unroll
        for (int n = 0; n < 4; ++n)
          acc[m][n] = mfma16(a[m], b[n], acc[m][n]);
    }
    __syncthreads();
  }
  // epilogue (C/D layout: col = lane&15, row = (lane>>4)*4 + i, verified m89)
  u16* outh = (u16*)out + (size_t)blockIdx.z * sC;
  float* outf = (float*)out + (size_t)blockIdx.z * sC;
#pragma unroll
  for (int m = 0; m < 4; ++m) {
    int row = m0 + wr * 64 + m * 16 + lh * 4;
#pragma unroll
    for (int n = 0; n < 4; ++n) {
      int col = n0 + wc * 64 + n * 16 + ll;
      float bv = (EPI == 0) ? 0.f : bias[col];
#pragma unroll
      for (int i = 0; i < 4; ++i) {
        float v = acc[m][n][i] + bv;
        size_t idx = (size_t)(row + i) * ldc + col;
        if (EPI == 2) v = 0.5f * v * (1.f + erff(v * 0.70710678118654752f));
        if (EPI == 3)
          outf[idx] = v + res[(size_t)blockIdx.z * sC + idx];
        else
          outh[idx] = f2bf(v);
      }
    }
  }
}

// ---------------------------------------------------------------------------
extern "C" void kernel_launch(void* const* d_in, const int* in_sizes, int n_in,
                              void* d_out, int out_size, void* d_ws, size_t ws_size,
                              hipStream_t stream) {
  const float* x     = (const float*)d_in[0];
  const float* ln1g  = (const float*)d_in[1];
  const float* ln1b  = (const float*)d_in[2];
  const float* Wq    = (const float*)d_in[3];
  const float* bq    = (const float*)d_in[4];
  const float* Wk    = (const float*)d_in[5];
  const float* bk    = (const float*)d_in[6];
  const float* Wv    = (const float*)d_in[7];
  const float* bv    = (const float*)d_in[8];
  const float* Wo    = (const float*)d_in[9];
  const float* bo    = (const float*)d_in[10];
  const float* ln2g  = (const float*)d_in[11];
  const float* ln2b  = (const float*)d_in[12];
  const float* W1    = (const float*)d_in[13];
  const float* b1    = (const float*)d_in[14];
  const float* W2    = (const float*)d_in[15];
  const float* b2    = (const float*)d_in[16];

  // workspace layout (120 MiB peak — matches round-1-proven footprint)
  char* base = (char*)d_ws;
  u16* Wqkvt = (u16*)base;                      // [1536][512]
  u16* Wot   = Wqkvt + 786432;                  // [512][512]
  u16* W1t   = Wot + 262144;                    // [2048][512]
  u16* W2t   = W1t + 1048576;                   // [512][2048]
  float* bqkv = (float*)(W2t + 1048576);        // [1536]
  u16* qkvb = (u16*)(base + (8u << 20));        // [16384][1536] bf16 (48 MiB)
  u16* Vt   = qkvb + (size_t)16384 * 1536;      // [4][512][4096] bf16 (16 MiB)
  u16* m1   = qkvb;                             // alias: [16384][2048] bf16 (qkv+Vt dead by MLP)
  u16* hb   = (u16*)(base + (8u << 20) + 67108864u);               // h/o/h2 [16384][512] bf16
  u16* scores = (u16*)(base + (8u << 20) + 67108864u + 16777216u); // [4096][4096] bf16 (32 MiB)
  float* x1 = (float*)scores;                   // alias: [16384][512] f32 (scores dead by Wo)

  const size_t S = 4096;
  dim3 tb(32, 8);
  pack_bias_k<<<6, 256, 0, stream>>>(bq, bk, bv, bqkv);
  tconv_w<<<dim3(16, 16), tb, 0, stream>>>(Wq, Wqkvt, 512, 512);
  tconv_w<<<dim3(16, 16), tb, 0, stream>>>(Wk, Wqkvt + 262144, 512, 512);
  tconv_w<<<dim3(16, 16), tb, 0, stream>>>(Wv, Wqkvt + 524288, 512, 512);
  tconv_w<<<dim3(16, 16), tb, 0, stream>>>(Wo, Wot, 512, 512);
  tconv_w<<<dim3(64, 16), tb, 0, stream>>>(W1, W1t, 512, 2048);
  tconv_w<<<dim3(16, 64), tb, 0, stream>>>(W2, W2t, 2048, 512);

  // h = LN1(x)
  ln_fwd<<<4096, 256, 0, stream>>>(x, ln1g, ln1b, hb);
  // qkv = h @ Wqkv + b
  gemm_bt<1><<<dim3(128, 12, 1), 256, 0, stream>>>(hb, 512, 0, Wqkvt, 512, 0, bqkv, nullptr,
                                                   qkvb, 1536, 0, 16384, 1536, 512);
  // Vt = transpose(v)
  tpose_v<<<dim3(16, 128, 4), tb, 0, stream>>>(qkvb, Vt);

  // attention, one batch at a time (scores buffer = 1 batch, 32 MiB)
  for (int b = 0; b < 4; ++b) {
    const u16* qk = qkvb + (size_t)b * S * 1536;
    // scores = Q(b) @ K(b)^T   (bf16, unscaled)
    gemm_bt<0><<<dim3(32, 32, 1), 256, 0, stream>>>(qk, 1536, 0, qk + 512, 1536, 0,
                                                    nullptr, nullptr, scores, 4096, 0,
                                                    4096, 4096, 512);
    // P = softmax(scores * scale), in place, normalized
    softmax_rows<<<4096, 256, 0, stream>>>(scores);
    // O(b) = P @ V(b)   (Vt is V^T so Bt layout is direct)
    gemm_bt<0><<<dim3(32, 4, 1), 256, 0, stream>>>(scores, 4096, 0,
                                                   Vt + (size_t)b * 512 * S, 4096, 0,
                                                   nullptr, nullptr,
                                                   hb + (size_t)b * S * 512, 512, 0,
                                                   4096, 512, 4096);
  }

  // x1 = x + o @ Wo + bo
  gemm_bt<3><<<dim3(128, 4, 1), 256, 0, stream>>>(hb, 512, 0, Wot, 512, 0, bo, x,
                                                  x1, 512, 0, 16384, 512, 512);
  // h2 = LN2(x1)
  ln_fwd<<<4096, 256, 0, stream>>>(x1, ln2g, ln2b, hb);
  // m1 = gelu(h2 @ W1 + b1)
  gemm_bt<2><<<dim3(128, 16, 1), 256, 0, stream>>>(hb, 512, 0, W1t, 512, 0, b1, nullptr,
                                                   m1, 2048, 0, 16384, 2048, 512);
  // out = x1 + m1 @ W2 + b2
  gemm_bt<3><<<dim3(128, 4, 1), 256, 0, stream>>>(m1, 2048, 0, W2t, 2048, 0, b2, x1,
                                                  (float*)d_out, 512, 0, 16384, 512, 2048);
}

// Round 4
// 432.094 us; speedup vs baseline: 2.0125x; 1.6070x over previous
//
#include <hip/hip_runtime.h>

typedef unsigned short u16;
typedef float f32x4 __attribute__((ext_vector_type(4)));
typedef __bf16 bf16x8 __attribute__((ext_vector_type(8)));

__device__ __forceinline__ u16 f2bf(float f) {
  unsigned u = __float_as_uint(f);
  u += 0x7fffu + ((u >> 16) & 1u);
  return (u16)(u >> 16);
}

__device__ __forceinline__ f32x4 mfma16(bf16x8 a, bf16x8 b, f32x4 c) {
  return __builtin_amdgcn_mfma_f32_16x16x32_bf16(a, b, c, 0, 0, 0);
}

// async global->LDS, 16B per lane; lds dest is wave-uniform base + lane*16
#define GLDS16(gp, lp)                                                            \
  __builtin_amdgcn_global_load_lds((const __attribute__((address_space(1))) void*)(gp), \
                                   (__attribute__((address_space(3))) void*)(lp), 16, 0, 0)

// ---------------------------------------------------------------------------
// Bias pack: bqkv[1536] = [bq | bk | bv]
// ---------------------------------------------------------------------------
__global__ void pack_bias_k(const float* __restrict__ bq, const float* __restrict__ bk,
                            const float* __restrict__ bv, float* __restrict__ bqkv) {
  int i = blockIdx.x * 256 + threadIdx.x;
  if (i < 512) bqkv[i] = bq[i];
  else if (i < 1024) bqkv[i] = bk[i - 512];
  else if (i < 1536) bqkv[i] = bv[i - 1024];
}

// ---------------------------------------------------------------------------
// Transpose+convert: out[C][R] (bf16) = in[R][C] (f32). Grid (C/32, R/32), block (32,8)
// ---------------------------------------------------------------------------
__global__ void tconv_w(const float* __restrict__ in, u16* __restrict__ out, int R, int C) {
  __shared__ float t[32][33];
  int c0 = blockIdx.x * 32, r0 = blockIdx.y * 32;
  int tx = threadIdx.x, ty = threadIdx.y;
#pragma unroll
  for (int j = 0; j < 4; ++j)
    t[ty * 4 + j][tx] = in[(size_t)(r0 + ty * 4 + j) * C + c0 + tx];
  __syncthreads();
#pragma unroll
  for (int j = 0; j < 4; ++j)
    out[(size_t)(c0 + ty * 4 + j) * R + r0 + tx] = f2bf(t[tx][ty * 4 + j]);
}

// ---------------------------------------------------------------------------
// V transpose (bf16->bf16): per batch z, in = qkv rows [4096] cols[1024..1536) stride 1536
// out = Vt[b][512][4096]. Grid (16,128,4), block (32,8)
// ---------------------------------------------------------------------------
__global__ void tpose_v(const u16* __restrict__ qkv, u16* __restrict__ Vt) {
  __shared__ u16 t[32][41];
  int b = blockIdx.z;
  int c0 = blockIdx.x * 32, r0 = blockIdx.y * 32;
  int tx = threadIdx.x, ty = threadIdx.y;
  const u16* in = qkv + (size_t)b * 4096 * 1536 + 1024;
  u16* outp = Vt + (size_t)b * 512 * 4096;
#pragma unroll
  for (int j = 0; j < 4; ++j)
    t[ty * 4 + j][tx] = in[(size_t)(r0 + ty * 4 + j) * 1536 + c0 + tx];
  __syncthreads();
#pragma unroll
  for (int j = 0; j < 4; ++j)
    outp[(size_t)(c0 + ty * 4 + j) * 4096 + r0 + tx] = t[tx][ty * 4 + j];
}

// ---------------------------------------------------------------------------
// LayerNorm: x f32 [R][512] -> out bf16 [R][512]. 1 wave per row, 4 rows/block.
// ---------------------------------------------------------------------------
__global__ __launch_bounds__(256) void ln_fwd(const float* __restrict__ x,
                                              const float* __restrict__ gw,
                                              const float* __restrict__ bw,
                                              u16* __restrict__ out) {
  int row = blockIdx.x * 4 + (threadIdx.x >> 6);
  int lane = threadIdx.x & 63;
  const float* xr = x + (size_t)row * 512;
  float xv[8], gv[8], bv[8];
  *(float4*)&xv[0] = *(const float4*)(xr + lane * 8);
  *(float4*)&xv[4] = *(const float4*)(xr + lane * 8 + 4);
  *(float4*)&gv[0] = *(const float4*)(gw + lane * 8);
  *(float4*)&gv[4] = *(const float4*)(gw + lane * 8 + 4);
  *(float4*)&bv[0] = *(const float4*)(bw + lane * 8);
  *(float4*)&bv[4] = *(const float4*)(bw + lane * 8 + 4);
  float sum = 0.f, sq = 0.f;
#pragma unroll
  for (int j = 0; j < 8; ++j) { sum += xv[j]; sq += xv[j] * xv[j]; }
#pragma unroll
  for (int d = 1; d < 64; d <<= 1) {
    sum += __shfl_xor(sum, d);
    sq += __shfl_xor(sq, d);
  }
  float mean = sum * (1.f / 512.f);
  float var = sq * (1.f / 512.f) - mean * mean;
  float rstd = rsqrtf(var + 1e-5f);
  union { uint4 u; u16 h[8]; } ob;
#pragma unroll
  for (int j = 0; j < 8; ++j)
    ob.h[j] = f2bf((xv[j] - mean) * rstd * gv[j] + bv[j]);
  *(uint4*)(out + (size_t)row * 512 + lane * 8) = ob.u;
}

// ---------------------------------------------------------------------------
// Row softmax in-place on bf16 scores [rows][4096]; applies scale 1/sqrt(512).
// 1 block (4 waves) per row; each thread owns 16 contiguous elements.
// ---------------------------------------------------------------------------
__global__ __launch_bounds__(256) void softmax_rows(u16* __restrict__ sc) {
  __shared__ float red[8];
  const int tid = threadIdx.x;
  const int lane = tid & 63, w = tid >> 6;
  u16* sr = sc + (size_t)blockIdx.x * 4096 + tid * 16;
  uint4 a = *(const uint4*)sr;
  uint4 b = *(const uint4*)(sr + 8);
  const u16* ap = (const u16*)&a;
  const u16* bp = (const u16*)&b;
  float v[16];
#pragma unroll
  for (int i = 0; i < 8; ++i) {
    v[i] = __uint_as_float((unsigned)ap[i] << 16);
    v[8 + i] = __uint_as_float((unsigned)bp[i] << 16);
  }
  float m = v[0];
#pragma unroll
  for (int i = 1; i < 16; ++i) m = fmaxf(m, v[i]);
#pragma unroll
  for (int d = 1; d < 64; d <<= 1) m = fmaxf(m, __shfl_xor(m, d));
  if (lane == 0) red[w] = m;
  __syncthreads();
  m = fmaxf(fmaxf(red[0], red[1]), fmaxf(red[2], red[3]));
  const float scale = 0.044194173824159216f;  // 512^-0.5
  float s = 0.f;
#pragma unroll
  for (int i = 0; i < 16; ++i) {
    v[i] = __expf((v[i] - m) * scale);
    s += v[i];
  }
#pragma unroll
  for (int d = 1; d < 64; d <<= 1) s += __shfl_xor(s, d);
  if (lane == 0) red[4 + w] = s;
  __syncthreads();
  s = (red[4] + red[5]) + (red[6] + red[7]);
  float inv = 1.f / s;
  union { uint4 u; u16 h[8]; } o1, o2;
#pragma unroll
  for (int i = 0; i < 8; ++i) {
    o1.h[i] = f2bf(v[i] * inv);
    o2.h[i] = f2bf(v[8 + i] * inv);
  }
  *(uint4*)sr = o1.u;
  *(uint4*)(sr + 8) = o2.u;
}

// ---------------------------------------------------------------------------
// GEMM: C[M][N] = A[M][K](bf16, row stride lda) * Bt[N][K](bf16, row stride ldb)^T
// Batched over blockIdx.z with element strides sA/sB/sC.
// EPI 0: out bf16 = acc               (scores, PV)
// EPI 1: out bf16 = acc + bias        (QKV)
// EPI 2: out bf16 = gelu(acc + bias)  (MLP1, tanh-form)
// EPI 3: out f32  = acc + bias + res  (Wo-proj, MLP2)
// 128x128 tile, BK=64, 256 threads (4 waves, 2x2), wave does 64x64 (4x4 frags).
// Staging: global_load_lds dwordx4, linear [128][64] LDS tiles (m97 structure).
// ---------------------------------------------------------------------------
template <int EPI>
__global__ __launch_bounds__(256, 2) void gemm_bt(const u16* __restrict__ A, int lda, size_t sA,
                                                  const u16* __restrict__ Bt, int ldb, size_t sB,
                                                  const float* __restrict__ bias,
                                                  const float* __restrict__ res,
                                                  void* __restrict__ out, int ldc, size_t sC,
                                                  int M, int N, int K) {
  __shared__ u16 As[128 * 64];
  __shared__ u16 Bs[128 * 64];
  const int tid = threadIdx.x;
  const int lane = tid & 63, w = tid >> 6;
  const int wr = w >> 1, wc = w & 1;
  const int m0 = blockIdx.x * 128, n0 = blockIdx.y * 128;
  const int lh = lane >> 4, ll = lane & 15;
  A += (size_t)blockIdx.z * sA;
  Bt += (size_t)blockIdx.z * sB;

  // wave w stages rows [w*32, w*32+32); each GLDS16 covers 8 rows (64 lanes x 16B)
  const int srow = w * 32 + (lane >> 3);
  const int scol = (lane & 7) * 8;
  const u16* ga = A + (size_t)(m0 + srow) * lda + scol;
  const u16* gb = Bt + (size_t)(n0 + srow) * ldb + scol;

  f32x4 acc[4][4] = {};
  const int nk = K >> 6;
  for (int kt = 0; kt < nk; ++kt) {
    const int k0 = kt << 6;
#pragma unroll
    for (int j = 0; j < 4; ++j) {
      GLDS16(ga + (size_t)(j * 8) * lda + k0, &As[(w * 32 + j * 8) * 64]);
      GLDS16(gb + (size_t)(j * 8) * ldb + k0, &Bs[(w * 32 + j * 8) * 64]);
    }
    __syncthreads();
#pragma unroll
    for (int ks = 0; ks < 2; ++ks) {
      bf16x8 a[4], b[4];
#pragma unroll
      for (int m = 0; m < 4; ++m)
        a[m] = *(const bf16x8*)&As[(wr * 64 + m * 16 + ll) * 64 + ks * 32 + lh * 8];
#pragma unroll
      for (int n = 0; n < 4; ++n)
        b[n] = *(const bf16x8*)&Bs[(wc * 64 + n * 16 + ll) * 64 + ks * 32 + lh * 8];
#pragma unroll
      for (int m = 0; m < 4; ++m)
#pragma unroll
        for (int n = 0; n < 4; ++n)
          acc[m][n] = mfma16(a[m], b[n], acc[m][n]);
    }
    __syncthreads();
  }
  // epilogue (C/D layout: col = lane&15, row = (lane>>4)*4 + i, verified m89)
  u16* outh = (u16*)out + (size_t)blockIdx.z * sC;
  float* outf = (float*)out + (size_t)blockIdx.z * sC;
#pragma unroll
  for (int m = 0; m < 4; ++m) {
    int row = m0 + wr * 64 + m * 16 + lh * 4;
#pragma unroll
    for (int n = 0; n < 4; ++n) {
      int col = n0 + wc * 64 + n * 16 + ll;
      float bv = (EPI == 0) ? 0.f : bias[col];
#pragma unroll
      for (int i = 0; i < 4; ++i) {
        float v = acc[m][n][i] + bv;
        size_t idx = (size_t)(row + i) * ldc + col;
        if (EPI == 2) {
          // tanh-form gelu: v*sigmoid(2y); max dev from erf-gelu ~3e-4 << bf16 ulp
          float y = 0.7978845608028654f * (v + 0.044715f * v * v * v);
          v = v / (1.f + __expf(-2.f * y));
        }
        if (EPI == 3)
          outf[idx] = v + res[(size_t)blockIdx.z * sC + idx];
        else
          outh[idx] = f2bf(v);
      }
    }
  }
}

// ---------------------------------------------------------------------------
extern "C" void kernel_launch(void* const* d_in, const int* in_sizes, int n_in,
                              void* d_out, int out_size, void* d_ws, size_t ws_size,
                              hipStream_t stream) {
  const float* x     = (const float*)d_in[0];
  const float* ln1g  = (const float*)d_in[1];
  const float* ln1b  = (const float*)d_in[2];
  const float* Wq    = (const float*)d_in[3];
  const float* bq    = (const float*)d_in[4];
  const float* Wk    = (const float*)d_in[5];
  const float* bk    = (const float*)d_in[6];
  const float* Wv    = (const float*)d_in[7];
  const float* bv    = (const float*)d_in[8];
  const float* Wo    = (const float*)d_in[9];
  const float* bo    = (const float*)d_in[10];
  const float* ln2g  = (const float*)d_in[11];
  const float* ln2b  = (const float*)d_in[12];
  const float* W1    = (const float*)d_in[13];
  const float* b1    = (const float*)d_in[14];
  const float* W2    = (const float*)d_in[15];
  const float* b2    = (const float*)d_in[16];

  // workspace layout:
  //   [0,8M):    weights (Wqkvt, Wot, W1t, W2t, bqkv)
  //   [8M,56M):  qkvb [16384][1536] bf16
  //   [56M,72M): Vt [4][512][4096] bf16        (m1 [16384][2048] aliases qkvb+Vt)
  //   [72M,88M): hb h/o/h2 [16384][512] bf16
  //   [88M,..):  scores [nb][4096][4096] bf16  (x1 f32 aliases scores)
  char* base = (char*)d_ws;
  u16* Wqkvt = (u16*)base;                      // [1536][512]
  u16* Wot   = Wqkvt + 786432;                  // [512][512]
  u16* W1t   = Wot + 262144;                    // [2048][512]
  u16* W2t   = W1t + 1048576;                   // [512][2048]
  float* bqkv = (float*)(W2t + 1048576);        // [1536]
  u16* qkvb = (u16*)(base + (8ull << 20));
  u16* Vt   = qkvb + (size_t)16384 * 1536;
  u16* m1   = qkvb;
  u16* hb   = (u16*)(base + (72ull << 20));
  const size_t sco_off = 88ull << 20;
  u16* scores = (u16*)(base + sco_off);
  float* x1 = (float*)scores;

  const size_t S = 4096;
  const size_t per_b = S * S * 2;  // 32 MiB per batch of scores
  int nb = 1;
  if (ws_size >= sco_off + 4 * per_b) nb = 4;
  else if (ws_size >= sco_off + 2 * per_b) nb = 2;

  dim3 tb(32, 8);
  pack_bias_k<<<6, 256, 0, stream>>>(bq, bk, bv, bqkv);
  tconv_w<<<dim3(16, 16), tb, 0, stream>>>(Wq, Wqkvt, 512, 512);
  tconv_w<<<dim3(16, 16), tb, 0, stream>>>(Wk, Wqkvt + 262144, 512, 512);
  tconv_w<<<dim3(16, 16), tb, 0, stream>>>(Wv, Wqkvt + 524288, 512, 512);
  tconv_w<<<dim3(16, 16), tb, 0, stream>>>(Wo, Wot, 512, 512);
  tconv_w<<<dim3(64, 16), tb, 0, stream>>>(W1, W1t, 512, 2048);
  tconv_w<<<dim3(16, 64), tb, 0, stream>>>(W2, W2t, 2048, 512);

  // h = LN1(x)
  ln_fwd<<<4096, 256, 0, stream>>>(x, ln1g, ln1b, hb);
  // qkv = h @ Wqkv + b
  gemm_bt<1><<<dim3(128, 12, 1), 256, 0, stream>>>(hb, 512, 0, Wqkvt, 512, 0, bqkv, nullptr,
                                                   qkvb, 1536, 0, 16384, 1536, 512);
  // Vt = transpose(v)
  tpose_v<<<dim3(16, 128, 4), tb, 0, stream>>>(qkvb, Vt);

  // attention, nb batches per chunk
  for (int b0 = 0; b0 < 4; b0 += nb) {
    int nz = (4 - b0) < nb ? (4 - b0) : nb;
    const u16* qk = qkvb + (size_t)b0 * S * 1536;
    // scores[z] = Q @ K^T (bf16, unscaled)
    gemm_bt<0><<<dim3(32, 32, nz), 256, 0, stream>>>(qk, 1536, S * 1536, qk + 512, 1536, S * 1536,
                                                     nullptr, nullptr, scores, 4096, S * S,
                                                     4096, 4096, 512);
    // P = softmax(scores * scale), in place
    softmax_rows<<<nz * 4096, 256, 0, stream>>>(scores);
    // O[z] = P @ V
    gemm_bt<0><<<dim3(32, 4, nz), 256, 0, stream>>>(scores, 4096, S * S,
                                                    Vt + (size_t)b0 * 512 * S, 4096, 512 * S,
                                                    nullptr, nullptr,
                                                    hb + (size_t)b0 * S * 512, 512, S * 512,
                                                    4096, 512, 4096);
  }

  // x1 = x + o @ Wo + bo
  gemm_bt<3><<<dim3(128, 4, 1), 256, 0, stream>>>(hb, 512, 0, Wot, 512, 0, bo, x,
                                                  x1, 512, 0, 16384, 512, 512);
  // h2 = LN2(x1)
  ln_fwd<<<4096, 256, 0, stream>>>(x1, ln2g, ln2b, hb);
  // m1 = gelu(h2 @ W1 + b1)
  gemm_bt<2><<<dim3(128, 16, 1), 256, 0, stream>>>(hb, 512, 0, W1t, 512, 0, b1, nullptr,
                                                   m1, 2048, 0, 16384, 2048, 512);
  // out = x1 + m1 @ W2 + b2
  gemm_bt<3><<<dim3(128, 4, 1), 256, 0, stream>>>(m1, 2048, 0, W2t, 2048, 0, b2, x1,
                                                  (float*)d_out, 512, 0, 16384, 512, 2048);
}